// Round 13
// baseline (90.910 us; speedup 1.0000x reference)
//
#include <hip/hip_runtime.h>
#include <math.h>

// Attention fwd: Q[N,64] K[N,64] V[N,64] fp32 -> O[N,64] fp32
// R12: LDS staging RETURNS (R7-R11's LDS-free loop was L2-BW-bound: every
// wave privately read K/V = 512MB L2 traffic; LDS sharing cuts it 4x) but
// now with FRAGMENT-MAJOR LDS layout = conflict-free ds_read_b128 by
// construction (64 lanes read 64 consecutive 16B slots; R4-R6's row-major
// tiles 4-way conflicted on every read).
//  - prepass: fragment-major Kf/Vf in ws (unchanged from R7).
//  - staging: global_load_lds(16B) linear (no address math), double-buffered,
//    counted vmcnt(4) never draining in-loop (R4 skeleton).
//  - compute: R11's pipelined STEP (SM(d1) overlaps PV first half), fixed-max
//    exp2 softmax M=8, deferred psum shuffle, setprio on MFMA.
//  - splits=8, separate high-parallelism combine.

typedef __bf16 bf16;
typedef __attribute__((ext_vector_type(8)))  __bf16 bf16x8;
typedef __attribute__((ext_vector_type(16))) float  f32x16;

#define DKc 64
#define DVc 64
#define TK  64
#define QB  128     // queries per block (4 waves x 32)
#define SCALE_LOG2E 0.1803368801111204f   // 0.125 * log2(e)
#define M2FIX 8.0f                        // fixed log2-domain max

__device__ __forceinline__ f32x16 mfma_bf16(bf16x8 a, bf16x8 b, f32x16 c) {
    return __builtin_amdgcn_mfma_f32_32x32x16_bf16(a, b, c, 0, 0, 0);
}
__device__ __forceinline__ int rp4(int r) {   // PV k-slot permute (involution)
    return ((r >> 2) & 1) * 8 + (r & 3) + ((r >> 3) << 2);
}

// ---- prepass: fragment-major Kf, Vf (4096 bf16 = 8KB per 64-key tile) -----
__global__ __launch_bounds__(256)
void prepass(const float* __restrict__ K, const float* __restrict__ V,
             bf16* __restrict__ Kf, bf16* __restrict__ Vf, int N) {
    const int b = blockIdx.x, tid = threadIdx.x;
    const int ntile = N / TK;
    if (b < ntile) {
        const size_t tbase = (size_t)b * 4096;
#pragma unroll
        for (int w = 0; w < 2; ++w) {
            int idx = w * 256 + tid;
            int sub = idx >> 8, f = (idx >> 6) & 3, l = idx & 63;
            int h = l >> 5, c = l & 31;
            const float* src = K + (size_t)(b * 64 + sub * 32 + c) * DKc + f * 16 + h * 8;
            float4 a  = *(const float4*)src;
            float4 b4 = *(const float4*)(src + 4);
            bf16x8 o;
            o[0]=(bf16)a.x;  o[1]=(bf16)a.y;  o[2]=(bf16)a.z;  o[3]=(bf16)a.w;
            o[4]=(bf16)b4.x; o[5]=(bf16)b4.y; o[6]=(bf16)b4.z; o[7]=(bf16)b4.w;
            *(bf16x8*)(Kf + tbase + (size_t)idx * 8) = o;
        }
    } else {
        const int T = b - ntile;
        __shared__ float sT[64][65];        // V tile transposed: sT[dv][key]
#pragma unroll
        for (int p = 0; p < 4; ++p) {
            int fi = p * 256 + tid;          // 1024 float4 = 64x64 tile
            int e0 = fi * 4;
            int key = e0 >> 6, dv = e0 & 63;
            float4 v = ((const float4*)(V + (size_t)T * 64 * DVc))[fi];
            sT[dv + 0][key] = v.x; sT[dv + 1][key] = v.y;
            sT[dv + 2][key] = v.z; sT[dv + 3][key] = v.w;
        }
        __syncthreads();
        const size_t tbase = (size_t)T * 4096;
#pragma unroll
        for (int w = 0; w < 2; ++w) {
            int idx = w * 256 + tid;
            int sub = idx >> 8, kb = (idx >> 6) & 3, l = idx & 63;
            int h = l >> 5, c = l & 31;
            bf16x8 o;
#pragma unroll
            for (int j = 0; j < 8; ++j)
                o[j] = (bf16)sT[sub * 32 + c][kb * 16 + rp4(h * 8 + j)];
            *(bf16x8*)(Vf + tbase + (size_t)idx * 8) = o;
        }
    }
}

// one attention step, within-tile pipelined: SM(d1) overlaps PV(kb=0,1)
#define STEP                                                                  \
    {                                                                         \
        f32x16 d0 = {0}, d1 = {0};                                            \
        __builtin_amdgcn_s_setprio(1);                                        \
        _Pragma("unroll")                                                     \
        for (int f = 0; f < 4; ++f) {                                         \
            d0 = mfma_bf16(kf[2*f],   qf[f], d0);                             \
            d1 = mfma_bf16(kf[2*f+1], qf[f], d1);                             \
        }                                                                     \
        __builtin_amdgcn_s_setprio(0);                                        \
        _Pragma("unroll")                                                     \
        for (int r = 0; r < 16; r += 4) {                                     \
            d0[r]   = __builtin_amdgcn_exp2f(d0[r]   - M2FIX); ps0 += d0[r];  \
            d0[r+1] = __builtin_amdgcn_exp2f(d0[r+1] - M2FIX); ps1 += d0[r+1];\
            d0[r+2] = __builtin_amdgcn_exp2f(d0[r+2] - M2FIX); ps2 += d0[r+2];\
            d0[r+3] = __builtin_amdgcn_exp2f(d0[r+3] - M2FIX); ps3 += d0[r+3];\
        }                                                                     \
        bf16x8 pa0, pa1;                                                      \
        _Pragma("unroll")                                                     \
        for (int j = 0; j < 8; ++j) { pa0[j] = (bf16)d0[j];                   \
                                      pa1[j] = (bf16)d0[8 + j]; }             \
        __builtin_amdgcn_s_setprio(1);                                        \
        O0 = mfma_bf16(pa0, vf[0], O0);                                       \
        O1 = mfma_bf16(pa0, vf[1], O1);                                       \
        O0 = mfma_bf16(pa1, vf[2], O0);                                       \
        O1 = mfma_bf16(pa1, vf[3], O1);                                       \
        __builtin_amdgcn_s_setprio(0);                                        \
        _Pragma("unroll")                                                     \
        for (int r = 0; r < 16; r += 4) {                                     \
            d1[r]   = __builtin_amdgcn_exp2f(d1[r]   - M2FIX); ps0 += d1[r];  \
            d1[r+1] = __builtin_amdgcn_exp2f(d1[r+1] - M2FIX); ps1 += d1[r+1];\
            d1[r+2] = __builtin_amdgcn_exp2f(d1[r+2] - M2FIX); ps2 += d1[r+2];\
            d1[r+3] = __builtin_amdgcn_exp2f(d1[r+3] - M2FIX); ps3 += d1[r+3];\
        }                                                                     \
        bf16x8 pa2, pa3;                                                      \
        _Pragma("unroll")                                                     \
        for (int j = 0; j < 8; ++j) { pa2[j] = (bf16)d1[j];                   \
                                      pa3[j] = (bf16)d1[8 + j]; }             \
        __builtin_amdgcn_s_setprio(1);                                        \
        O0 = mfma_bf16(pa2, vf[4], O0);                                       \
        O1 = mfma_bf16(pa2, vf[5], O1);                                       \
        O0 = mfma_bf16(pa3, vf[6], O0);                                       \
        O1 = mfma_bf16(pa3, vf[7], O1);                                       \
        __builtin_amdgcn_s_setprio(0);                                        \
    }

// ---- main flash kernel: LDS-staged fragment-major tiles -------------------
__global__ __launch_bounds__(256, 2)
void attn_fwd_mfma(const float* __restrict__ Q, const bf16* __restrict__ Kf,
                   const bf16* __restrict__ Vf,
                   float* __restrict__ Opart, float* __restrict__ Lpart,
                   float* __restrict__ Out, int N, int splits, int chunk) {
    // double-buffered fragment-major tiles: 8KB each matrix per buffer
    __shared__ __align__(16) short sK[2][4096];
    __shared__ __align__(16) short sV[2][4096];

    const int tid  = threadIdx.x;
    const int wid  = tid >> 6;
    const int lane = tid & 63;
    const int l31  = lane & 31;
    const int h    = lane >> 5;

    const int qbase = blockIdx.x * QB + wid * 32;
    const int q     = qbase + l31;
    const int sp    = blockIdx.y;

    // Q fragments: qf[f][j] = Q[q][f*16+h*8+j] * SCALE_LOG2E
    bf16x8 qf[4];
#pragma unroll
    for (int f = 0; f < 4; ++f) {
        const float* qp = Q + (size_t)q * DKc + f * 16 + h * 8;
        float4 a = *(const float4*)qp;
        float4 b = *(const float4*)(qp + 4);
        qf[f][0] = (bf16)(a.x * SCALE_LOG2E); qf[f][1] = (bf16)(a.y * SCALE_LOG2E);
        qf[f][2] = (bf16)(a.z * SCALE_LOG2E); qf[f][3] = (bf16)(a.w * SCALE_LOG2E);
        qf[f][4] = (bf16)(b.x * SCALE_LOG2E); qf[f][5] = (bf16)(b.y * SCALE_LOG2E);
        qf[f][6] = (bf16)(b.z * SCALE_LOG2E); qf[f][7] = (bf16)(b.w * SCALE_LOG2E);
    }

    f32x16 O0 = {0}, O1 = {0};
    float ps0 = 0.f, ps1 = 0.f, ps2 = 0.f, ps3 = 0.f;

    const int k0 = sp * chunk;
    int k1 = k0 + chunk; if (k1 > N) k1 = N;
    const int tile0  = k0 >> 6;
    const int ntiles = (k1 - k0) >> 6;

    const char* KfB = (const char*)Kf;
    const char* VfB = (const char*)Vf;

    // stage one tile (8KB K + 8KB V) into buf: 4 x global_load_lds(16B)/thread,
    // LINEAR dest (fragment-major source is already in MFMA order)
    auto stage = [&](int buf, int tile) {
        char* sKb = (char*)&sK[buf][0];
        char* sVb = (char*)&sV[buf][0];
#pragma unroll
        for (int p = 0; p < 2; ++p) {
            int o = p * 4096 + wid * 1024 + lane * 16;
            __builtin_amdgcn_global_load_lds(
                (const __attribute__((address_space(1))) void*)(KfB + (size_t)tile * 8192 + o),
                (__attribute__((address_space(3))) void*)(sKb + p * 4096 + wid * 1024),
                16, 0, 0);
        }
#pragma unroll
        for (int p = 0; p < 2; ++p) {
            int o = p * 4096 + wid * 1024 + lane * 16;
            __builtin_amdgcn_global_load_lds(
                (const __attribute__((address_space(1))) void*)(VfB + (size_t)tile * 8192 + o),
                (__attribute__((address_space(3))) void*)(sVb + p * 4096 + wid * 1024),
                16, 0, 0);
        }
    };

    stage(0, tile0);
    int cur = 0;

    for (int it = 0; it < ntiles; ++it) {
        if (it + 1 < ntiles) {
            stage(cur ^ 1, tile0 + it + 1);
            // wait only the 4 OLDEST vmem ops (current tile); next stays in flight
            asm volatile("s_waitcnt vmcnt(4)" ::: "memory");
        } else {
            asm volatile("s_waitcnt vmcnt(0)" ::: "memory");
        }
        __builtin_amdgcn_sched_barrier(0);
        __builtin_amdgcn_s_barrier();

        // fragment reads: 64 lanes hit 64 CONSECUTIVE 16B slots -> conflict-free
        const char* sKc = (const char*)&sK[cur][0];
        const char* sVc = (const char*)&sV[cur][0];
        bf16x8 kf[8], vf[8];
#pragma unroll
        for (int f = 0; f < 4; ++f) {
            kf[2*f]   = *(const bf16x8*)(sKc + (f * 64 + lane) * 16);
            kf[2*f+1] = *(const bf16x8*)(sKc + 4096 + (f * 64 + lane) * 16);
        }
#pragma unroll
        for (int kb = 0; kb < 4; ++kb) {
            vf[2*kb]   = *(const bf16x8*)(sVc + (kb * 64 + lane) * 16);
            vf[2*kb+1] = *(const bf16x8*)(sVc + 4096 + (kb * 64 + lane) * 16);
        }

        STEP

        __builtin_amdgcn_s_barrier();   // all waves done reading buf[cur]
        cur ^= 1;
    }

    float lsum = (ps0 + ps1) + (ps2 + ps3);
    lsum += __shfl_xor(lsum, 32);

    if (splits == 1) {
        float inv = 1.f / lsum;
#pragma unroll
        for (int r = 0; r < 16; ++r) {
            int qr = (r & 3) + 8 * (r >> 2) + 4 * h;
            float fr = __shfl(inv, (lane & 32) | qr);
            int qq = qbase + qr;
            Out[(size_t)qq * DVc + l31]      = O0[r] * fr;
            Out[(size_t)qq * DVc + 32 + l31] = O1[r] * fr;
        }
    } else {
#pragma unroll
        for (int r = 0; r < 16; ++r) {
            int qr = (r & 3) + 8 * (r >> 2) + 4 * h;
            int qq = qbase + qr;
            size_t off = ((size_t)sp * N + qq) * DVc;
            Opart[off + l31]      = O0[r];
            Opart[off + 32 + l31] = O1[r];
        }
        if (lane < 32) Lpart[(size_t)sp * N + q] = lsum;
    }
}

// ---- combine: linear (fixed max), high-parallelism grid -------------------
__global__ __launch_bounds__(256)
void attn_combine(const float* __restrict__ Opart, const float* __restrict__ Lpart,
                  float* __restrict__ Out, int N, int splits) {
    const int t  = blockIdx.x * blockDim.x + threadIdx.x;  // [0, N*16)
    const int q  = t >> 4;
    const int d4 = t & 15;

    float4 acc = make_float4(0.f, 0.f, 0.f, 0.f);
    float  L = 0.f;
    for (int s = 0; s < splits; ++s) {
        L += Lpart[(size_t)s * N + q];
        float4 ov = *(const float4*)(Opart + ((size_t)s * N + q) * DVc + d4 * 4);
        acc.x += ov.x; acc.y += ov.y; acc.z += ov.z; acc.w += ov.w;
    }
    float inv = 1.f / L;
    *(float4*)(Out + (size_t)q * DVc + d4 * 4) =
        make_float4(acc.x * inv, acc.y * inv, acc.z * inv, acc.w * inv);
}

extern "C" void kernel_launch(void* const* d_in, const int* in_sizes, int n_in,
                              void* d_out, int out_size, void* d_ws, size_t ws_size,
                              hipStream_t stream) {
    const float* Q = (const float*)d_in[0];
    const float* K = (const float*)d_in[1];
    const float* V = (const float*)d_in[2];
    float* Out = (float*)d_out;

    const int N = in_sizes[0] / DKc;   // 8192

    // ws: Kf | Vf (bf16, N*64 each, fragment-major) | Opart | Lpart
    const size_t bfbytes = (size_t)N * DKc * sizeof(short);
    bf16* Kf = (bf16*)d_ws;
    bf16* Vf = (bf16*)((char*)d_ws + bfbytes);
    char* rest = (char*)d_ws + 2 * bfbytes;
    size_t rest_sz = (ws_size > 2 * bfbytes) ? ws_size - 2 * bfbytes : 0;

    int splits = 8;     // 512 blocks = 2 blocks/CU, single residency pass
    while (splits > 1 &&
           (size_t)splits * (size_t)N * (DVc + 1) * sizeof(float) > rest_sz)
        splits >>= 1;
    int chunk = (N + splits - 1) / splits;
    chunk = ((chunk + TK - 1) / TK) * TK;

    float* Opart = (float*)rest;
    float* Lpart = Opart + (size_t)splits * N * DVc;

    const int ntile = N / TK;
    prepass<<<2 * ntile, 256, 0, stream>>>(K, V, Kf, Vf, N);

    dim3 grid(N / QB, splits);
    attn_fwd_mfma<<<grid, 256, 0, stream>>>(Q, Kf, Vf, Opart, Lpart, Out,
                                            N, splits, chunk);
    if (splits > 1) {
        int total = N * 16;
        attn_combine<<<total / 256, 256, 0, stream>>>(Opart, Lpart, Out, N, splits);
    }
}